// Round 8
// baseline (117.343 us; speedup 1.0000x reference)
//
#include <hip/hip_runtime.h>
#include <hip/hip_fp16.h>

// ShiftDecoderNet fused kernel for MI355X (gfx950).  R8.
// R5-R7: kernel pinned ~40us across occupancy x4, VALU -50%, all pipes <35%.
// Surviving theory: synchronized post-barrier cold-start stalls (compiler
// drains vmcnt(0) before s_barrier -> every stage starts with 200-900cyc L2
// loads, all waves+blocks phase-locked). R8: cross-barrier prefetch - issue
// every post-barrier global load BEFORE the preceding barrier (scalars+a_bits
// at start; W2 ks=0 frags after GEMM1 MFMAs; all W3 frags after GEMM2 MFMAs).
// launch_bounds (256,4): VGPR cap 128 (wave count is free per R5/R6 evidence).
//
// GEMMs: mfma_f32_16x16x32_bf16.  A-frag: m=lane&15, k=(lane>>4)*8+j.
// C/D: col=lane&15, row=(lane>>4)*4+reg  (verified layouts).

typedef short s8v __attribute__((ext_vector_type(8)));   // 8 bf16 payloads
typedef float f4v __attribute__((ext_vector_type(4)));

#define HPAD 264   // short elements; row stride 528B breaks pow2 bank conflicts
#define PPAD 68    // float elements

// d_ws layout (bf16 elements)
#define OFF_W1F 0        // 16nt x 2kc x 64lane x 8  = 16384
#define OFF_W2F 16384    // 16nt x 8kc x 64lane x 8  = 65536
#define OFF_W3F 81920    //  4nt x 8kc x 64lane x 8  = 16384
#define OFF_B1  98304
#define OFF_G1  98560
#define OFF_BE1 98816
#define OFF_B2  99072
#define OFF_G2  99328
#define OFF_BE2 99584
#define OFF_B3  99840    // 64

__device__ __forceinline__ float b2f(unsigned short u) {
    union { unsigned int i; float f; } v; v.i = ((unsigned int)u) << 16; return v.f;
}
__device__ __forceinline__ unsigned short f2b(float f) {
    union { float f; unsigned int i; } v; v.f = f;
    return (unsigned short)((v.i + 0x7fffu + ((v.i >> 16) & 1u)) >> 16);  // RNE
}
// packed f32x2 -> bf16x2 (lo=a, hi=b), RNE. One VALU inst.
__device__ __forceinline__ unsigned int cvtpk(float a, float b) {
    unsigned int r;
    asm("v_cvt_pk_bf16_f32 %0, %1, %2" : "=v"(r) : "v"(a), "v"(b));
    return r;
}
__device__ __forceinline__ int h2i(__half2 h) { union { __half2 h; int i; } u; u.h = h; return u.i; }
__device__ __forceinline__ __half2 i2h(int i) { union { __half2 h; int i; } u; u.i = i; return u.h; }

__device__ __forceinline__ bool probe_bf16(const void* a_bits) {
    // a_bits is exactly {0.0,1.0}. f32 dwords: {0x0,0x3F800000} (low half 0).
    // packed-bf16 dwords: low half 0x3F80 w.p. 1/2 per word.
    unsigned int wv = ((const unsigned int*)a_bits)[threadIdx.x & 63];
    return __ballot((wv & 0xffffu) == 0x3f80u) != 0ULL;
}

// ============ kernel 0: convert + swizzle weights into d_ws (bf16) ============
__global__ __launch_bounds__(256) void convert_kernel(
    const void* __restrict__ a_probe,
    const void* __restrict__ W1, const void* __restrict__ W2, const void* __restrict__ W3,
    const void* __restrict__ b1, const void* __restrict__ g1, const void* __restrict__ be1,
    const void* __restrict__ b2, const void* __restrict__ g2, const void* __restrict__ be2,
    const void* __restrict__ b3,
    unsigned short* __restrict__ ws)
{
    const bool isbf = probe_bf16(a_probe);
    const int t = blockIdx.x * 256 + threadIdx.x;

    if (t < 12288) {            // weight 8-element chunks, frag order
        const void* W; int K, idx, dstbase;
        if (t < 2048)       { idx = t;         W = W1; K = 64;  dstbase = OFF_W1F + idx * 8; }
        else if (t < 10240) { idx = t - 2048;  W = W2; K = 256; dstbase = OFF_W2F + idx * 8; }
        else                { idx = t - 10240; W = W3; K = 256; dstbase = OFF_W3F + idx * 8; }
        int nt, kc, lane;
        if (t < 2048) { nt = idx >> 7; kc = (idx >> 6) & 1; lane = idx & 63; }
        else          { nt = idx >> 9; kc = (idx >> 6) & 7; lane = idx & 63; }
        const int row = nt * 16 + (lane & 15);
        const int col = kc * 32 + (lane >> 4) * 8;
        const int src = row * K + col;
        s8v o;
        if (isbf) {
            o = *(const s8v*)((const unsigned short*)W + src);
        } else {
            const float* f = (const float*)W + src;
#pragma unroll
            for (int j = 0; j < 8; ++j) o[j] = (short)f2b(f[j]);
        }
        *(s8v*)(ws + dstbase) = o;
    } else if (t < 12488) {     // bias/gamma/beta 8-element chunks
        const int v = t - 12288;
        const void* srcp; int base, off;
        if (v < 32)       { srcp = b1;  base = OFF_B1;  off = v * 8; }
        else if (v < 64)  { srcp = g1;  base = OFF_G1;  off = (v - 32) * 8; }
        else if (v < 96)  { srcp = be1; base = OFF_BE1; off = (v - 64) * 8; }
        else if (v < 128) { srcp = b2;  base = OFF_B2;  off = (v - 96) * 8; }
        else if (v < 160) { srcp = g2;  base = OFF_G2;  off = (v - 128) * 8; }
        else if (v < 192) { srcp = be2; base = OFF_BE2; off = (v - 160) * 8; }
        else              { srcp = b3;  base = OFF_B3;  off = (v - 192) * 8; }
#pragma unroll
        for (int j = 0; j < 8; ++j)
            ws[base + off + j] = isbf ? ((const unsigned short*)srcp)[off + j]
                                      : f2b(((const float*)srcp)[off + j]);
    }
}

// ======================= main fused pipeline ==================================
template<bool BF16>
__device__ __forceinline__ float loadS(const void* p, int idx) {
    if constexpr (BF16) return b2f(((const unsigned short*)p)[idx]);
    else return ((const float*)p)[idx];
}
template<bool BF16>
__device__ __forceinline__ s8v loadA8(const void* p, int idx) {   // activations
    if constexpr (BF16) {
        return *(const s8v*)((const unsigned short*)p + idx);
    } else {
        const float* f = (const float*)p + idx;
        f4v a = *(const f4v*)f;
        f4v b = *(const f4v*)(f + 4);
        union { s8v s; unsigned int u[4]; } r;
        r.u[0] = cvtpk(a[0], a[1]);
        r.u[1] = cvtpk(a[2], a[3]);
        r.u[2] = cvtpk(b[0], b[1]);
        r.u[3] = cvtpk(b[2], b[3]);
        return r.s;
    }
}
template<bool BF16>
__device__ __forceinline__ void storeO(void* p, int idx, float v) {
    if constexpr (BF16) ((unsigned short*)p)[idx] = f2b(v);
    else ((float*)p)[idx] = v;
}

template<bool BF16>
__device__ __forceinline__ void pipeline(
    const void* a_bits, const void* shifts, const unsigned short* ws, void* out,
    short* Hs, float* Ps, float* SS)
{
    const int tid = threadIdx.x;
    const int h = tid >> 6;        // wave = N-quarter 0..3
    const int l = tid & 63;
    const int q = l >> 4;
    const int c = l & 15;
    const int ntb = h << 2;        // first nt of this wave's quarter
    const int grow0 = (int)blockIdx.x << 4;   // 16 rows/block
    const int row = q * 4;         // +r = this lane's C/D rows

    // ---- PREFETCH (cross-barrier): all post-barrier cold globals issued here ----
    float b1v[4], g1v[4], be1v[4], b2v[4], g2v[4], be2v[4];
#pragma unroll
    for (int i = 0; i < 4; ++i) {
        const int o = (ntb + i) * 16 + c;
        b1v[i]  = b2f(ws[OFF_B1  + o]);
        g1v[i]  = b2f(ws[OFF_G1  + o]);
        be1v[i] = b2f(ws[OFF_BE1 + o]);
        b2v[i]  = b2f(ws[OFF_B2  + o]);
        g2v[i]  = b2f(ws[OFF_G2  + o]);
        be2v[i] = b2f(ws[OFF_BE2 + o]);
    }
    const float b3s = b2f(ws[OFF_B3 + h * 16 + c]);
    float aj0[2], aj1[2];          // Toeplitz a_bits (consumed after bar6)
#pragma unroll
    for (int jj = 0; jj < 2; ++jj) {
        const int j = h * 2 + jj;
        aj0[jj] = loadS<BF16>(a_bits, (grow0 + j) * 64 + l);
        aj1[jj] = loadS<BF16>(a_bits, (grow0 + j + 8) * 64 + l);
    }

    // ===== GEMM1: [16x64] @ W1^T -> cols [ntb*16, +64) =====
    f4v acc1[4];
#pragma unroll
    for (int i = 0; i < 4; ++i) acc1[i] = (f4v){0.f, 0.f, 0.f, 0.f};

    const s8v xa0 = loadA8<BF16>(shifts, (grow0 + c) * 64 + q * 8);
    const s8v xa1 = loadA8<BF16>(shifts, (grow0 + c) * 64 + 32 + q * 8);
#pragma unroll
    for (int i = 0; i < 4; ++i) {
        const int nt = ntb + i;
        s8v wb0 = *(const s8v*)(ws + OFF_W1F + ((nt * 2 + 0) * 64 + l) * 8);
        s8v wb1 = *(const s8v*)(ws + OFF_W1F + ((nt * 2 + 1) * 64 + l) * 8);
        acc1[i] = __builtin_amdgcn_mfma_f32_16x16x32_bf16(xa0, wb0, acc1[i], 0, 0, 0);
        acc1[i] = __builtin_amdgcn_mfma_f32_16x16x32_bf16(xa1, wb1, acc1[i], 0, 0, 0);
    }

    // PREFETCH GEMM2 ks=0 weight frags (consumed right after bar2; latency
    // covered by the LN1 epilogue below, completed by the bar2 vmcnt drain).
    s8v w2pf[4];
#pragma unroll
    for (int i = 0; i < 4; ++i)
        w2pf[i] = *(const s8v*)(ws + OFF_W2F + (((ntb + i) * 8 + 0) * 64 + l) * 8);

    {
        float s[4] = {0, 0, 0, 0}, ss[4] = {0, 0, 0, 0};
#pragma unroll
        for (int i = 0; i < 4; ++i) {
#pragma unroll
            for (int r = 0; r < 4; ++r) {
                float v = acc1[i][r] + b1v[i];
                acc1[i][r] = v;
                s[r] += v; ss[r] += v * v;
            }
        }
#pragma unroll
        for (int m = 1; m <= 8; m <<= 1)
#pragma unroll
            for (int r = 0; r < 4; ++r) {
                s[r]  += __shfl_xor(s[r],  m, 64);
                ss[r] += __shfl_xor(ss[r], m, 64);
            }
        if (c == 0)
#pragma unroll
            for (int r = 0; r < 4; ++r) {
                SS[(h * 16 + row + r) * 2 + 0] = s[r];
                SS[(h * 16 + row + r) * 2 + 1] = ss[r];
            }
        __syncthreads();   // bar1: LN1 stats
#pragma unroll
        for (int r = 0; r < 4; ++r) {
            float st = 0.f, sq = 0.f;
#pragma unroll
            for (int wv = 0; wv < 4; ++wv) {
                st += SS[(wv * 16 + row + r) * 2 + 0];
                sq += SS[(wv * 16 + row + r) * 2 + 1];
            }
            float mean = st * (1.0f / 256.0f);
            float var  = fmaxf(sq * (1.0f / 256.0f) - mean * mean, 0.0f);
            s[r] = mean; ss[r] = rsqrtf(var + 1e-5f);
        }
#pragma unroll
        for (int i = 0; i < 4; ++i) {
            const int nt = ntb + i;
            float y[4];
#pragma unroll
            for (int r = 0; r < 4; ++r)
                y[r] = fmaxf((acc1[i][r] - s[r]) * ss[r] * g1v[i] + be1v[i], 0.0f);
            unsigned int u01 = cvtpk(y[0], y[1]);
            unsigned int u23 = cvtpk(y[2], y[3]);
            Hs[(row + 0) * HPAD + nt * 16 + c] = (short)(u01 & 0xffffu);
            Hs[(row + 1) * HPAD + nt * 16 + c] = (short)(u01 >> 16);
            Hs[(row + 2) * HPAD + nt * 16 + c] = (short)(u23 & 0xffffu);
            Hs[(row + 3) * HPAD + nt * 16 + c] = (short)(u23 >> 16);
        }
    }
    __syncthreads();   // bar2: Hs(v1) ready, SS(LN1) reads done

    // ===== GEMM2: [16x256] @ W2^T -> cols [ntb*16, +64) =====
    f4v acc2[4];
#pragma unroll
    for (int i = 0; i < 4; ++i) acc2[i] = (f4v){0.f, 0.f, 0.f, 0.f};
#pragma unroll
    for (int ks = 0; ks < 8; ++ks) {
        s8v af = *(const s8v*)&Hs[c * HPAD + ks * 32 + q * 8];
#pragma unroll
        for (int i = 0; i < 4; ++i) {
            s8v bf_ = (ks == 0) ? w2pf[i]
                    : *(const s8v*)(ws + OFF_W2F + (((ntb + i) * 8 + ks) * 64 + l) * 8);
            acc2[i] = __builtin_amdgcn_mfma_f32_16x16x32_bf16(af, bf_, acc2[i], 0, 0, 0);
        }
    }

    // PREFETCH all GEMM3 W3 frags (consumed after bar4; latency covered by the
    // LN2 epilogue; held across bar3+bar4 in VGPRs).
    s8v w3pf[8];
#pragma unroll
    for (int ks = 0; ks < 8; ++ks)
        w3pf[ks] = *(const s8v*)(ws + OFF_W3F + ((h * 8 + ks) * 64 + l) * 8);

    {
        float s[4] = {0, 0, 0, 0}, ss[4] = {0, 0, 0, 0};
#pragma unroll
        for (int i = 0; i < 4; ++i) {
#pragma unroll
            for (int r = 0; r < 4; ++r) {
                float v = acc2[i][r] + b2v[i];
                acc2[i][r] = v;
                s[r] += v; ss[r] += v * v;
            }
        }
#pragma unroll
        for (int m = 1; m <= 8; m <<= 1)
#pragma unroll
            for (int r = 0; r < 4; ++r) {
                s[r]  += __shfl_xor(s[r],  m, 64);
                ss[r] += __shfl_xor(ss[r], m, 64);
            }
        if (c == 0)
#pragma unroll
            for (int r = 0; r < 4; ++r) {
                SS[(h * 16 + row + r) * 2 + 0] = s[r];
                SS[(h * 16 + row + r) * 2 + 1] = ss[r];
            }
        __syncthreads();   // bar3: LN2 stats (all GEMM2 Hs reads also done)
#pragma unroll
        for (int r = 0; r < 4; ++r) {
            float st = 0.f, sq = 0.f;
#pragma unroll
            for (int wv = 0; wv < 4; ++wv) {
                st += SS[(wv * 16 + row + r) * 2 + 0];
                sq += SS[(wv * 16 + row + r) * 2 + 1];
            }
            float mean = st * (1.0f / 256.0f);
            float var  = fmaxf(sq * (1.0f / 256.0f) - mean * mean, 0.0f);
            s[r] = mean; ss[r] = rsqrtf(var + 1e-5f);
        }
#pragma unroll
        for (int i = 0; i < 4; ++i) {
            const int nt = ntb + i;
            float y[4];
#pragma unroll
            for (int r = 0; r < 4; ++r)
                y[r] = fmaxf((acc2[i][r] - s[r]) * ss[r] * g2v[i] + be2v[i], 0.0f);
            unsigned int u01 = cvtpk(y[0], y[1]);
            unsigned int u23 = cvtpk(y[2], y[3]);
            Hs[(row + 0) * HPAD + nt * 16 + c] = (short)(u01 & 0xffffu);
            Hs[(row + 1) * HPAD + nt * 16 + c] = (short)(u01 >> 16);
            Hs[(row + 2) * HPAD + nt * 16 + c] = (short)(u23 & 0xffffu);
            Hs[(row + 3) * HPAD + nt * 16 + c] = (short)(u23 >> 16);
        }
    }
    __syncthreads();   // bar4: Hs(v2) ready, SS(LN2) reads done

    // ===== GEMM3 (split): wave h computes cols [h*16, +16); softmax cross-wave ===
    // No max-subtraction: logits bounded (|x| ~< 3 post-LN), exp is safe.
    f4v acc3 = (f4v){0.f, 0.f, 0.f, 0.f};
#pragma unroll
    for (int ks = 0; ks < 8; ++ks) {
        s8v af = *(const s8v*)&Hs[c * HPAD + ks * 32 + q * 8];
        acc3 = __builtin_amdgcn_mfma_f32_16x16x32_bf16(af, w3pf[ks], acc3, 0, 0, 0);
    }
    {
        float sum[4];
#pragma unroll
        for (int r = 0; r < 4; ++r) {
            float e = __expf(acc3[r] + b3s);
            acc3[r] = e;
            sum[r] = e;
        }
#pragma unroll
        for (int m = 1; m <= 8; m <<= 1)
#pragma unroll
            for (int r = 0; r < 4; ++r)
                sum[r] += __shfl_xor(sum[r], m, 64);
        if (c == 0)
#pragma unroll
            for (int r = 0; r < 4; ++r)
                SS[(h * 16 + row + r) * 2 + 0] = sum[r];
        __syncthreads();   // bar5: sum stats; also all Hs reads done -> Ps overlay safe
#pragma unroll
        for (int r = 0; r < 4; ++r) {
            float S = SS[(0 * 16 + row + r) * 2 + 0] + SS[(1 * 16 + row + r) * 2 + 0]
                    + SS[(2 * 16 + row + r) * 2 + 0] + SS[(3 * 16 + row + r) * 2 + 0];
            float inv = __builtin_amdgcn_rcpf(S);   // |rel err| ~1e-7, fine at 1.5e-2 tol
            Ps[(row + r) * PPAD + h * 16 + c] = acc3[r] * inv;
        }
    }
    __syncthreads();   // bar6: Ps ready

    // ===== Toeplitz: out[m,i] = sum_{s<=i} p[m,s]*a[m,i-s], DPP wave_shr =====
    // 2 j-pairs per wave, a-values prefetched at kernel start. r starts as a[i];
    // step s: acc += p[s]*r; r = wave_shr(r) (0-fill -> causal mask free).
#pragma unroll
    for (int jj = 0; jj < 2; ++jj) {
        const int j = h * 2 + jj;
        const int m0 = j, m1 = j + 8;
        __half2 pph = __floats2half2_rn(Ps[m0 * PPAD + l], Ps[m1 * PPAD + l]);
        const int ppi = h2i(pph);
        __half2 aah = __floats2half2_rn(aj0[jj], aj1[jj]);
        int rr = h2i(aah);
        __half2 acc = __float2half2_rn(0.0f);
#pragma unroll
        for (int s = 0; s < 64; ++s) {
            const int spi = __builtin_amdgcn_readlane(ppi, s);
            acc = __hfma2(i2h(spi), i2h(rr), acc);
            if (s < 63)
                rr = __builtin_amdgcn_update_dpp(0, rr, 0x138, 0xF, 0xF, true); // wave_shr:1
        }
        storeO<BF16>(out, (grow0 + m0) * 64 + l, __low2float(acc));
        storeO<BF16>(out, (grow0 + m1) * 64 + l, __high2float(acc));
    }
}

__global__ __launch_bounds__(256, 4) void shiftdec_kernel(
    const void* __restrict__ a_bits, const void* __restrict__ shifts,
    const unsigned short* __restrict__ ws, void* __restrict__ out)
{
    __shared__ __align__(16) char smem[16 * HPAD * 2];   // 8448 B; Ps overlays Hs
    __shared__ __align__(16) float SSb[4 * 16 * 2];      // 512 B stat exchange
    short* Hs = (short*)smem;
    float* Ps = (float*)smem;                            // 16*68*4 = 4352 B <= 8448

    if (probe_bf16(a_bits))
        pipeline<true>(a_bits, shifts, ws, out, Hs, Ps, SSb);
    else
        pipeline<false>(a_bits, shifts, ws, out, Hs, Ps, SSb);
}

extern "C" void kernel_launch(void* const* d_in, const int* in_sizes, int n_in,
                              void* d_out, int out_size, void* d_ws, size_t ws_size,
                              hipStream_t stream) {
    const int B = in_sizes[0] / 64;      // rows (32768)
    const int grid = B / 16;             // 16 rows per block -> 2048 blocks

    hipLaunchKernelGGL(convert_kernel, dim3(49), dim3(256), 0, stream,
                       d_in[0], d_in[2], d_in[6], d_in[10],
                       d_in[3], d_in[4], d_in[5], d_in[7], d_in[8], d_in[9], d_in[11],
                       (unsigned short*)d_ws);
    hipLaunchKernelGGL(shiftdec_kernel, dim3(grid), dim3(256), 0, stream,
                       d_in[0], d_in[1], (const unsigned short*)d_ws, d_out);
}

// Round 9
// 116.258 us; speedup vs baseline: 1.0093x; 1.0093x over previous
//
#include <hip/hip_runtime.h>
#include <hip/hip_fp16.h>

// ShiftDecoderNet fused kernel for MI355X (gfx950).  R9.
// R5-R8 post-mortems: kernel pinned ~40us; occupancy x4, VALU -20%, prefetch
// all null -> binding constraint is barrier-drain convoying (6 s_barriers,
// each with full vmcnt/lgkmcnt drain, little work between them). R9: merge
// softmax's two barriers into one - unnormalized e goes to a SEPARATE Ps
// buffer (no Hs overlay -> no read/write hazard), per-row sums to SS, single
// barrier; 1/S folded into Toeplitz half-pack (p<=1 before half cvt, no
// overflow). 5 barriers. R8 prefetch reverted (regressed).
//
// GEMMs: mfma_f32_16x16x32_bf16.  A-frag: m=lane&15, k=(lane>>4)*8+j.
// C/D: col=lane&15, row=(lane>>4)*4+reg  (verified layouts).

typedef short s8v __attribute__((ext_vector_type(8)));   // 8 bf16 payloads
typedef float f4v __attribute__((ext_vector_type(4)));

#define HPAD 264   // short elements; row stride 528B breaks pow2 bank conflicts
#define PPAD 68    // float elements

// d_ws layout (bf16 elements)
#define OFF_W1F 0        // 16nt x 2kc x 64lane x 8  = 16384
#define OFF_W2F 16384    // 16nt x 8kc x 64lane x 8  = 65536
#define OFF_W3F 81920    //  4nt x 8kc x 64lane x 8  = 16384
#define OFF_B1  98304
#define OFF_G1  98560
#define OFF_BE1 98816
#define OFF_B2  99072
#define OFF_G2  99328
#define OFF_BE2 99584
#define OFF_B3  99840    // 64

__device__ __forceinline__ float b2f(unsigned short u) {
    union { unsigned int i; float f; } v; v.i = ((unsigned int)u) << 16; return v.f;
}
__device__ __forceinline__ unsigned short f2b(float f) {
    union { float f; unsigned int i; } v; v.f = f;
    return (unsigned short)((v.i + 0x7fffu + ((v.i >> 16) & 1u)) >> 16);  // RNE
}
// packed f32x2 -> bf16x2 (lo=a, hi=b), RNE. One VALU inst.
__device__ __forceinline__ unsigned int cvtpk(float a, float b) {
    unsigned int r;
    asm("v_cvt_pk_bf16_f32 %0, %1, %2" : "=v"(r) : "v"(a), "v"(b));
    return r;
}
__device__ __forceinline__ int h2i(__half2 h) { union { __half2 h; int i; } u; u.h = h; return u.i; }
__device__ __forceinline__ __half2 i2h(int i) { union { __half2 h; int i; } u; u.i = i; return u.h; }

__device__ __forceinline__ bool probe_bf16(const void* a_bits) {
    // a_bits is exactly {0.0,1.0}. f32 dwords: {0x0,0x3F800000} (low half 0).
    // packed-bf16 dwords: low half 0x3F80 w.p. 1/2 per word.
    unsigned int wv = ((const unsigned int*)a_bits)[threadIdx.x & 63];
    return __ballot((wv & 0xffffu) == 0x3f80u) != 0ULL;
}

// ============ kernel 0: convert + swizzle weights into d_ws (bf16) ============
__global__ __launch_bounds__(256) void convert_kernel(
    const void* __restrict__ a_probe,
    const void* __restrict__ W1, const void* __restrict__ W2, const void* __restrict__ W3,
    const void* __restrict__ b1, const void* __restrict__ g1, const void* __restrict__ be1,
    const void* __restrict__ b2, const void* __restrict__ g2, const void* __restrict__ be2,
    const void* __restrict__ b3,
    unsigned short* __restrict__ ws)
{
    const bool isbf = probe_bf16(a_probe);
    const int t = blockIdx.x * 256 + threadIdx.x;

    if (t < 12288) {            // weight 8-element chunks, frag order
        const void* W; int K, idx, dstbase;
        if (t < 2048)       { idx = t;         W = W1; K = 64;  dstbase = OFF_W1F + idx * 8; }
        else if (t < 10240) { idx = t - 2048;  W = W2; K = 256; dstbase = OFF_W2F + idx * 8; }
        else                { idx = t - 10240; W = W3; K = 256; dstbase = OFF_W3F + idx * 8; }
        int nt, kc, lane;
        if (t < 2048) { nt = idx >> 7; kc = (idx >> 6) & 1; lane = idx & 63; }
        else          { nt = idx >> 9; kc = (idx >> 6) & 7; lane = idx & 63; }
        const int row = nt * 16 + (lane & 15);
        const int col = kc * 32 + (lane >> 4) * 8;
        const int src = row * K + col;
        s8v o;
        if (isbf) {
            o = *(const s8v*)((const unsigned short*)W + src);
        } else {
            const float* f = (const float*)W + src;
#pragma unroll
            for (int j = 0; j < 8; ++j) o[j] = (short)f2b(f[j]);
        }
        *(s8v*)(ws + dstbase) = o;
    } else if (t < 12488) {     // bias/gamma/beta 8-element chunks
        const int v = t - 12288;
        const void* srcp; int base, off;
        if (v < 32)       { srcp = b1;  base = OFF_B1;  off = v * 8; }
        else if (v < 64)  { srcp = g1;  base = OFF_G1;  off = (v - 32) * 8; }
        else if (v < 96)  { srcp = be1; base = OFF_BE1; off = (v - 64) * 8; }
        else if (v < 128) { srcp = b2;  base = OFF_B2;  off = (v - 96) * 8; }
        else if (v < 160) { srcp = g2;  base = OFF_G2;  off = (v - 128) * 8; }
        else if (v < 192) { srcp = be2; base = OFF_BE2; off = (v - 160) * 8; }
        else              { srcp = b3;  base = OFF_B3;  off = (v - 192) * 8; }
#pragma unroll
        for (int j = 0; j < 8; ++j)
            ws[base + off + j] = isbf ? ((const unsigned short*)srcp)[off + j]
                                      : f2b(((const float*)srcp)[off + j]);
    }
}

// ======================= main fused pipeline ==================================
template<bool BF16>
__device__ __forceinline__ float loadS(const void* p, int idx) {
    if constexpr (BF16) return b2f(((const unsigned short*)p)[idx]);
    else return ((const float*)p)[idx];
}
template<bool BF16>
__device__ __forceinline__ s8v loadA8(const void* p, int idx) {   // activations
    if constexpr (BF16) {
        return *(const s8v*)((const unsigned short*)p + idx);
    } else {
        const float* f = (const float*)p + idx;
        f4v a = *(const f4v*)f;
        f4v b = *(const f4v*)(f + 4);
        union { s8v s; unsigned int u[4]; } r;
        r.u[0] = cvtpk(a[0], a[1]);
        r.u[1] = cvtpk(a[2], a[3]);
        r.u[2] = cvtpk(b[0], b[1]);
        r.u[3] = cvtpk(b[2], b[3]);
        return r.s;
    }
}
template<bool BF16>
__device__ __forceinline__ void storeO(void* p, int idx, float v) {
    if constexpr (BF16) ((unsigned short*)p)[idx] = f2b(v);
    else ((float*)p)[idx] = v;
}

template<bool BF16>
__device__ __forceinline__ void pipeline(
    const void* a_bits, const void* shifts, const unsigned short* ws, void* out,
    short* Hs, float* Ps, float* SS)
{
    const int tid = threadIdx.x;
    const int h = tid >> 6;        // wave = N-quarter 0..3
    const int l = tid & 63;
    const int q = l >> 4;
    const int c = l & 15;
    const int ntb = h << 2;        // first nt of this wave's quarter
    const int grow0 = (int)blockIdx.x << 4;   // 16 rows/block
    const int row = q * 4;         // +r = this lane's C/D rows

    // ===== GEMM1: [16x64] @ W1^T -> cols [ntb*16, +64) =====
    f4v acc1[4];
#pragma unroll
    for (int i = 0; i < 4; ++i) acc1[i] = (f4v){0.f, 0.f, 0.f, 0.f};

    const s8v xa0 = loadA8<BF16>(shifts, (grow0 + c) * 64 + q * 8);
    const s8v xa1 = loadA8<BF16>(shifts, (grow0 + c) * 64 + 32 + q * 8);
#pragma unroll
    for (int i = 0; i < 4; ++i) {
        const int nt = ntb + i;
        s8v wb0 = *(const s8v*)(ws + OFF_W1F + ((nt * 2 + 0) * 64 + l) * 8);
        s8v wb1 = *(const s8v*)(ws + OFF_W1F + ((nt * 2 + 1) * 64 + l) * 8);
        acc1[i] = __builtin_amdgcn_mfma_f32_16x16x32_bf16(xa0, wb0, acc1[i], 0, 0, 0);
        acc1[i] = __builtin_amdgcn_mfma_f32_16x16x32_bf16(xa1, wb1, acc1[i], 0, 0, 0);
    }
    {
        float s[4] = {0, 0, 0, 0}, ss[4] = {0, 0, 0, 0};
#pragma unroll
        for (int i = 0; i < 4; ++i) {
            float bias = b2f(ws[OFF_B1 + (ntb + i) * 16 + c]);
#pragma unroll
            for (int r = 0; r < 4; ++r) {
                float v = acc1[i][r] + bias;
                acc1[i][r] = v;
                s[r] += v; ss[r] += v * v;
            }
        }
#pragma unroll
        for (int m = 1; m <= 8; m <<= 1)
#pragma unroll
            for (int r = 0; r < 4; ++r) {
                s[r]  += __shfl_xor(s[r],  m, 64);
                ss[r] += __shfl_xor(ss[r], m, 64);
            }
        if (c == 0)
#pragma unroll
            for (int r = 0; r < 4; ++r) {
                SS[(h * 16 + row + r) * 2 + 0] = s[r];
                SS[(h * 16 + row + r) * 2 + 1] = ss[r];
            }
        __syncthreads();   // bar1: LN1 stats
#pragma unroll
        for (int r = 0; r < 4; ++r) {
            float st = 0.f, sq = 0.f;
#pragma unroll
            for (int wv = 0; wv < 4; ++wv) {
                st += SS[(wv * 16 + row + r) * 2 + 0];
                sq += SS[(wv * 16 + row + r) * 2 + 1];
            }
            float mean = st * (1.0f / 256.0f);
            float var  = fmaxf(sq * (1.0f / 256.0f) - mean * mean, 0.0f);
            s[r] = mean; ss[r] = rsqrtf(var + 1e-5f);
        }
#pragma unroll
        for (int i = 0; i < 4; ++i) {
            const int nt = ntb + i;
            float gg = b2f(ws[OFF_G1 + nt * 16 + c]);
            float bb = b2f(ws[OFF_BE1 + nt * 16 + c]);
            float y[4];
#pragma unroll
            for (int r = 0; r < 4; ++r)
                y[r] = fmaxf((acc1[i][r] - s[r]) * ss[r] * gg + bb, 0.0f);
            unsigned int u01 = cvtpk(y[0], y[1]);
            unsigned int u23 = cvtpk(y[2], y[3]);
            Hs[(row + 0) * HPAD + nt * 16 + c] = (short)(u01 & 0xffffu);
            Hs[(row + 1) * HPAD + nt * 16 + c] = (short)(u01 >> 16);
            Hs[(row + 2) * HPAD + nt * 16 + c] = (short)(u23 & 0xffffu);
            Hs[(row + 3) * HPAD + nt * 16 + c] = (short)(u23 >> 16);
        }
    }
    __syncthreads();   // bar2: Hs(v1) ready, SS(LN1) reads done

    // ===== GEMM2: [16x256] @ W2^T -> cols [ntb*16, +64) =====
    f4v acc2[4];
#pragma unroll
    for (int i = 0; i < 4; ++i) acc2[i] = (f4v){0.f, 0.f, 0.f, 0.f};
#pragma unroll
    for (int ks = 0; ks < 8; ++ks) {
        s8v af = *(const s8v*)&Hs[c * HPAD + ks * 32 + q * 8];
#pragma unroll
        for (int i = 0; i < 4; ++i) {
            const int nt = ntb + i;
            s8v bf_ = *(const s8v*)(ws + OFF_W2F + ((nt * 8 + ks) * 64 + l) * 8);
            acc2[i] = __builtin_amdgcn_mfma_f32_16x16x32_bf16(af, bf_, acc2[i], 0, 0, 0);
        }
    }
    {
        float s[4] = {0, 0, 0, 0}, ss[4] = {0, 0, 0, 0};
#pragma unroll
        for (int i = 0; i < 4; ++i) {
            float bias = b2f(ws[OFF_B2 + (ntb + i) * 16 + c]);
#pragma unroll
            for (int r = 0; r < 4; ++r) {
                float v = acc2[i][r] + bias;
                acc2[i][r] = v;
                s[r] += v; ss[r] += v * v;
            }
        }
#pragma unroll
        for (int m = 1; m <= 8; m <<= 1)
#pragma unroll
            for (int r = 0; r < 4; ++r) {
                s[r]  += __shfl_xor(s[r],  m, 64);
                ss[r] += __shfl_xor(ss[r], m, 64);
            }
        if (c == 0)
#pragma unroll
            for (int r = 0; r < 4; ++r) {
                SS[(h * 16 + row + r) * 2 + 0] = s[r];
                SS[(h * 16 + row + r) * 2 + 1] = ss[r];
            }
        __syncthreads();   // bar3: LN2 stats (all GEMM2 Hs reads also done)
#pragma unroll
        for (int r = 0; r < 4; ++r) {
            float st = 0.f, sq = 0.f;
#pragma unroll
            for (int wv = 0; wv < 4; ++wv) {
                st += SS[(wv * 16 + row + r) * 2 + 0];
                sq += SS[(wv * 16 + row + r) * 2 + 1];
            }
            float mean = st * (1.0f / 256.0f);
            float var  = fmaxf(sq * (1.0f / 256.0f) - mean * mean, 0.0f);
            s[r] = mean; ss[r] = rsqrtf(var + 1e-5f);
        }
#pragma unroll
        for (int i = 0; i < 4; ++i) {
            const int nt = ntb + i;
            float gg = b2f(ws[OFF_G2 + nt * 16 + c]);
            float bb = b2f(ws[OFF_BE2 + nt * 16 + c]);
            float y[4];
#pragma unroll
            for (int r = 0; r < 4; ++r)
                y[r] = fmaxf((acc2[i][r] - s[r]) * ss[r] * gg + bb, 0.0f);
            unsigned int u01 = cvtpk(y[0], y[1]);
            unsigned int u23 = cvtpk(y[2], y[3]);
            Hs[(row + 0) * HPAD + nt * 16 + c] = (short)(u01 & 0xffffu);
            Hs[(row + 1) * HPAD + nt * 16 + c] = (short)(u01 >> 16);
            Hs[(row + 2) * HPAD + nt * 16 + c] = (short)(u23 & 0xffffu);
            Hs[(row + 3) * HPAD + nt * 16 + c] = (short)(u23 >> 16);
        }
    }
    __syncthreads();   // bar4: Hs(v2) ready, SS(LN2) reads done

    // ===== GEMM3 (split): wave h computes cols [h*16, +16); softmax merged-bar ===
    // No max-subtraction (logits bounded, exp-safe). Unnormalized e -> Ps
    // (separate buffer, no overlay hazard); per-row partial sums -> SS slot1.
    // ONE barrier covers both; 1/S folded into Toeplitz half-pack.
    f4v acc3 = (f4v){0.f, 0.f, 0.f, 0.f};
#pragma unroll
    for (int ks = 0; ks < 8; ++ks) {
        s8v af = *(const s8v*)&Hs[c * HPAD + ks * 32 + q * 8];
        s8v bf_ = *(const s8v*)(ws + OFF_W3F + ((h * 8 + ks) * 64 + l) * 8);
        acc3 = __builtin_amdgcn_mfma_f32_16x16x32_bf16(af, bf_, acc3, 0, 0, 0);
    }
    {
        const float bias = b2f(ws[OFF_B3 + h * 16 + c]);
        float sum[4];
#pragma unroll
        for (int r = 0; r < 4; ++r) {
            float e = __expf(acc3[r] + bias);
            Ps[(row + r) * PPAD + h * 16 + c] = e;   // unnormalized
            sum[r] = e;
        }
#pragma unroll
        for (int m = 1; m <= 8; m <<= 1)
#pragma unroll
            for (int r = 0; r < 4; ++r)
                sum[r] += __shfl_xor(sum[r], m, 64);
        if (c == 0)
#pragma unroll
            for (int r = 0; r < 4; ++r)
                SS[(h * 16 + row + r) * 2 + 1] = sum[r];
    }
    __syncthreads();   // bar5: Ps(e) + partial sums visible

    // ===== Toeplitz: out[m,i] = (1/S_m) * sum_{s<=i} e[m,s]*a[m,i-s] =====
    // 2 j-pairs per wave. Normalize during half-pack (p<=1, no overflow).
    // r starts as a[i]; step s: acc += p[s]*r; r = wave_shr(r) (0-fill).
#pragma unroll
    for (int jj = 0; jj < 2; ++jj) {
        const int j = h * 2 + jj;
        const int m0 = j, m1 = j + 8;
        float S0 = 0.f, S1 = 0.f;
#pragma unroll
        for (int wv = 0; wv < 4; ++wv) {
            S0 += SS[(wv * 16 + m0) * 2 + 1];
            S1 += SS[(wv * 16 + m1) * 2 + 1];
        }
        const float i0 = __builtin_amdgcn_rcpf(S0);
        const float i1 = __builtin_amdgcn_rcpf(S1);
        __half2 pph = __floats2half2_rn(Ps[m0 * PPAD + l] * i0,
                                        Ps[m1 * PPAD + l] * i1);
        const int ppi = h2i(pph);
        __half2 aah = __floats2half2_rn(loadS<BF16>(a_bits, (grow0 + m0) * 64 + l),
                                        loadS<BF16>(a_bits, (grow0 + m1) * 64 + l));
        int rr = h2i(aah);
        __half2 acc = __float2half2_rn(0.0f);
#pragma unroll
        for (int s = 0; s < 64; ++s) {
            const int spi = __builtin_amdgcn_readlane(ppi, s);
            acc = __hfma2(i2h(spi), i2h(rr), acc);
            if (s < 63)
                rr = __builtin_amdgcn_update_dpp(0, rr, 0x138, 0xF, 0xF, true); // wave_shr:1
        }
        storeO<BF16>(out, (grow0 + m0) * 64 + l, __low2float(acc));
        storeO<BF16>(out, (grow0 + m1) * 64 + l, __high2float(acc));
    }
}

__global__ __launch_bounds__(256, 8) void shiftdec_kernel(
    const void* __restrict__ a_bits, const void* __restrict__ shifts,
    const unsigned short* __restrict__ ws, void* __restrict__ out)
{
    __shared__ __align__(16) short Hs[16 * HPAD];        // 8448 B
    __shared__ __align__(16) float Ps[16 * PPAD];        // 4352 B (separate: no overlay)
    __shared__ __align__(16) float SSb[4 * 16 * 2];      // 512 B stat exchange

    if (probe_bf16(a_bits))
        pipeline<true>(a_bits, shifts, ws, out, Hs, Ps, SSb);
    else
        pipeline<false>(a_bits, shifts, ws, out, Hs, Ps, SSb);
}

extern "C" void kernel_launch(void* const* d_in, const int* in_sizes, int n_in,
                              void* d_out, int out_size, void* d_ws, size_t ws_size,
                              hipStream_t stream) {
    const int B = in_sizes[0] / 64;      // rows (32768)
    const int grid = B / 16;             // 16 rows per block -> 2048 blocks

    hipLaunchKernelGGL(convert_kernel, dim3(49), dim3(256), 0, stream,
                       d_in[0], d_in[2], d_in[6], d_in[10],
                       d_in[3], d_in[4], d_in[5], d_in[7], d_in[8], d_in[9], d_in[11],
                       (unsigned short*)d_ws);
    hipLaunchKernelGGL(shiftdec_kernel, dim3(grid), dim3(256), 0, stream,
                       d_in[0], d_in[1], (const unsigned short*)d_ws, d_out);
}

// Round 10
// 111.445 us; speedup vs baseline: 1.0529x; 1.0432x over previous
//
#include <hip/hip_runtime.h>
#include <hip/hip_fp16.h>

// ShiftDecoderNet fused kernel for MI355X (gfx950).  R10.
// R5-R9: kernel pinned ~40us. Null results: occupancy 16->32 waves/CU (R6,R8),
// VALU -20% (R7), VMEM prefetch (R8), barrier 6->5 (R9). Saturation at ~16
// waves/CU on an unmeasured resource. Last coherent lever: BARRIER GRANULARITY.
// R10: 128-thread / 2-wave blocks (2-way N-split, 8 tiles/wave). Each s_barrier
// couples only 2 waves; 8 independently-phased blocks/CU smooth per-stage
// resource demand. Work arithmetic neutral (per-wave tiles x2, waves/CU 16 -
// proven equivalent to 32 by R8). 5 barriers. If flat -> declare ceiling.
//
// GEMMs: mfma_f32_16x16x32_bf16.  A-frag: m=lane&15, k=(lane>>4)*8+j.
// C/D: col=lane&15, row=(lane>>4)*4+reg  (verified layouts).

typedef short s8v __attribute__((ext_vector_type(8)));   // 8 bf16 payloads
typedef float f4v __attribute__((ext_vector_type(4)));

#define HPAD 264   // short elements; row stride 528B breaks pow2 bank conflicts
#define PPAD 68    // float elements

// d_ws layout (bf16 elements)
#define OFF_W1F 0        // 16nt x 2kc x 64lane x 8  = 16384
#define OFF_W2F 16384    // 16nt x 8kc x 64lane x 8  = 65536
#define OFF_W3F 81920    //  4nt x 8kc x 64lane x 8  = 16384
#define OFF_B1  98304
#define OFF_G1  98560
#define OFF_BE1 98816
#define OFF_B2  99072
#define OFF_G2  99328
#define OFF_BE2 99584
#define OFF_B3  99840    // 64

__device__ __forceinline__ float b2f(unsigned short u) {
    union { unsigned int i; float f; } v; v.i = ((unsigned int)u) << 16; return v.f;
}
__device__ __forceinline__ unsigned short f2b(float f) {
    union { float f; unsigned int i; } v; v.f = f;
    return (unsigned short)((v.i + 0x7fffu + ((v.i >> 16) & 1u)) >> 16);  // RNE
}
// packed f32x2 -> bf16x2 (lo=a, hi=b), RNE. One VALU inst.
__device__ __forceinline__ unsigned int cvtpk(float a, float b) {
    unsigned int r;
    asm("v_cvt_pk_bf16_f32 %0, %1, %2" : "=v"(r) : "v"(a), "v"(b));
    return r;
}
__device__ __forceinline__ int h2i(__half2 h) { union { __half2 h; int i; } u; u.h = h; return u.i; }
__device__ __forceinline__ __half2 i2h(int i) { union { __half2 h; int i; } u; u.i = i; return u.h; }

__device__ __forceinline__ bool probe_bf16(const void* a_bits) {
    // a_bits is exactly {0.0,1.0}. f32 dwords: {0x0,0x3F800000} (low half 0).
    // packed-bf16 dwords: low half 0x3F80 w.p. 1/2 per word.
    unsigned int wv = ((const unsigned int*)a_bits)[threadIdx.x & 63];
    return __ballot((wv & 0xffffu) == 0x3f80u) != 0ULL;
}

// ============ kernel 0: convert + swizzle weights into d_ws (bf16) ============
__global__ __launch_bounds__(256) void convert_kernel(
    const void* __restrict__ a_probe,
    const void* __restrict__ W1, const void* __restrict__ W2, const void* __restrict__ W3,
    const void* __restrict__ b1, const void* __restrict__ g1, const void* __restrict__ be1,
    const void* __restrict__ b2, const void* __restrict__ g2, const void* __restrict__ be2,
    const void* __restrict__ b3,
    unsigned short* __restrict__ ws)
{
    const bool isbf = probe_bf16(a_probe);
    const int t = blockIdx.x * 256 + threadIdx.x;

    if (t < 12288) {            // weight 8-element chunks, frag order
        const void* W; int K, idx, dstbase;
        if (t < 2048)       { idx = t;         W = W1; K = 64;  dstbase = OFF_W1F + idx * 8; }
        else if (t < 10240) { idx = t - 2048;  W = W2; K = 256; dstbase = OFF_W2F + idx * 8; }
        else                { idx = t - 10240; W = W3; K = 256; dstbase = OFF_W3F + idx * 8; }
        int nt, kc, lane;
        if (t < 2048) { nt = idx >> 7; kc = (idx >> 6) & 1; lane = idx & 63; }
        else          { nt = idx >> 9; kc = (idx >> 6) & 7; lane = idx & 63; }
        const int row = nt * 16 + (lane & 15);
        const int col = kc * 32 + (lane >> 4) * 8;
        const int src = row * K + col;
        s8v o;
        if (isbf) {
            o = *(const s8v*)((const unsigned short*)W + src);
        } else {
            const float* f = (const float*)W + src;
#pragma unroll
            for (int j = 0; j < 8; ++j) o[j] = (short)f2b(f[j]);
        }
        *(s8v*)(ws + dstbase) = o;
    } else if (t < 12488) {     // bias/gamma/beta 8-element chunks
        const int v = t - 12288;
        const void* srcp; int base, off;
        if (v < 32)       { srcp = b1;  base = OFF_B1;  off = v * 8; }
        else if (v < 64)  { srcp = g1;  base = OFF_G1;  off = (v - 32) * 8; }
        else if (v < 96)  { srcp = be1; base = OFF_BE1; off = (v - 64) * 8; }
        else if (v < 128) { srcp = b2;  base = OFF_B2;  off = (v - 96) * 8; }
        else if (v < 160) { srcp = g2;  base = OFF_G2;  off = (v - 128) * 8; }
        else if (v < 192) { srcp = be2; base = OFF_BE2; off = (v - 160) * 8; }
        else              { srcp = b3;  base = OFF_B3;  off = (v - 192) * 8; }
#pragma unroll
        for (int j = 0; j < 8; ++j)
            ws[base + off + j] = isbf ? ((const unsigned short*)srcp)[off + j]
                                      : f2b(((const float*)srcp)[off + j]);
    }
}

// ======================= main fused pipeline ==================================
template<bool BF16>
__device__ __forceinline__ float loadS(const void* p, int idx) {
    if constexpr (BF16) return b2f(((const unsigned short*)p)[idx]);
    else return ((const float*)p)[idx];
}
template<bool BF16>
__device__ __forceinline__ s8v loadA8(const void* p, int idx) {   // activations
    if constexpr (BF16) {
        return *(const s8v*)((const unsigned short*)p + idx);
    } else {
        const float* f = (const float*)p + idx;
        f4v a = *(const f4v*)f;
        f4v b = *(const f4v*)(f + 4);
        union { s8v s; unsigned int u[4]; } r;
        r.u[0] = cvtpk(a[0], a[1]);
        r.u[1] = cvtpk(a[2], a[3]);
        r.u[2] = cvtpk(b[0], b[1]);
        r.u[3] = cvtpk(b[2], b[3]);
        return r.s;
    }
}
template<bool BF16>
__device__ __forceinline__ void storeO(void* p, int idx, float v) {
    if constexpr (BF16) ((unsigned short*)p)[idx] = f2b(v);
    else ((float*)p)[idx] = v;
}

template<bool BF16>
__device__ __forceinline__ void pipeline(
    const void* a_bits, const void* shifts, const unsigned short* ws, void* out,
    short* Hs, float* Ps, float* SS)
{
    const int tid = threadIdx.x;
    const int h = tid >> 6;        // wave = N-half 0..1
    const int l = tid & 63;
    const int q = l >> 4;
    const int c = l & 15;
    const int ntb = h << 3;        // first nt of this wave's half (0 or 8)
    const int grow0 = (int)blockIdx.x << 4;   // 16 rows/block
    const int row = q * 4;         // +r = this lane's C/D rows

    // ===== GEMM1: [16x64] @ W1^T -> cols [ntb*16, +128) =====
    f4v acc1[8];
#pragma unroll
    for (int i = 0; i < 8; ++i) acc1[i] = (f4v){0.f, 0.f, 0.f, 0.f};

    const s8v xa0 = loadA8<BF16>(shifts, (grow0 + c) * 64 + q * 8);
    const s8v xa1 = loadA8<BF16>(shifts, (grow0 + c) * 64 + 32 + q * 8);
#pragma unroll
    for (int i = 0; i < 8; ++i) {
        const int nt = ntb + i;
        s8v wb0 = *(const s8v*)(ws + OFF_W1F + ((nt * 2 + 0) * 64 + l) * 8);
        s8v wb1 = *(const s8v*)(ws + OFF_W1F + ((nt * 2 + 1) * 64 + l) * 8);
        acc1[i] = __builtin_amdgcn_mfma_f32_16x16x32_bf16(xa0, wb0, acc1[i], 0, 0, 0);
        acc1[i] = __builtin_amdgcn_mfma_f32_16x16x32_bf16(xa1, wb1, acc1[i], 0, 0, 0);
    }
    {
        float s[4] = {0, 0, 0, 0}, ss[4] = {0, 0, 0, 0};
#pragma unroll
        for (int i = 0; i < 8; ++i) {
            float bias = b2f(ws[OFF_B1 + (ntb + i) * 16 + c]);
#pragma unroll
            for (int r = 0; r < 4; ++r) {
                float v = acc1[i][r] + bias;
                acc1[i][r] = v;
                s[r] += v; ss[r] += v * v;
            }
        }
#pragma unroll
        for (int m = 1; m <= 8; m <<= 1)
#pragma unroll
            for (int r = 0; r < 4; ++r) {
                s[r]  += __shfl_xor(s[r],  m, 64);
                ss[r] += __shfl_xor(ss[r], m, 64);
            }
        if (c == 0)
#pragma unroll
            for (int r = 0; r < 4; ++r) {
                SS[(h * 16 + row + r) * 2 + 0] = s[r];
                SS[(h * 16 + row + r) * 2 + 1] = ss[r];
            }
        __syncthreads();   // bar1: LN1 stats (2 waves)
#pragma unroll
        for (int r = 0; r < 4; ++r) {
            float st = SS[(0 * 16 + row + r) * 2 + 0] + SS[(1 * 16 + row + r) * 2 + 0];
            float sq = SS[(0 * 16 + row + r) * 2 + 1] + SS[(1 * 16 + row + r) * 2 + 1];
            float mean = st * (1.0f / 256.0f);
            float var  = fmaxf(sq * (1.0f / 256.0f) - mean * mean, 0.0f);
            s[r] = mean; ss[r] = rsqrtf(var + 1e-5f);
        }
#pragma unroll
        for (int i = 0; i < 8; ++i) {
            const int nt = ntb + i;
            float gg = b2f(ws[OFF_G1 + nt * 16 + c]);
            float bb = b2f(ws[OFF_BE1 + nt * 16 + c]);
            float y[4];
#pragma unroll
            for (int r = 0; r < 4; ++r)
                y[r] = fmaxf((acc1[i][r] - s[r]) * ss[r] * gg + bb, 0.0f);
            unsigned int u01 = cvtpk(y[0], y[1]);
            unsigned int u23 = cvtpk(y[2], y[3]);
            Hs[(row + 0) * HPAD + nt * 16 + c] = (short)(u01 & 0xffffu);
            Hs[(row + 1) * HPAD + nt * 16 + c] = (short)(u01 >> 16);
            Hs[(row + 2) * HPAD + nt * 16 + c] = (short)(u23 & 0xffffu);
            Hs[(row + 3) * HPAD + nt * 16 + c] = (short)(u23 >> 16);
        }
    }
    __syncthreads();   // bar2: Hs(v1) ready, SS(LN1) reads done

    // ===== GEMM2: [16x256] @ W2^T -> cols [ntb*16, +128) =====
    f4v acc2[8];
#pragma unroll
    for (int i = 0; i < 8; ++i) acc2[i] = (f4v){0.f, 0.f, 0.f, 0.f};
#pragma unroll
    for (int ks = 0; ks < 8; ++ks) {
        s8v af = *(const s8v*)&Hs[c * HPAD + ks * 32 + q * 8];
#pragma unroll
        for (int i = 0; i < 8; ++i) {
            const int nt = ntb + i;
            s8v bf_ = *(const s8v*)(ws + OFF_W2F + ((nt * 8 + ks) * 64 + l) * 8);
            acc2[i] = __builtin_amdgcn_mfma_f32_16x16x32_bf16(af, bf_, acc2[i], 0, 0, 0);
        }
    }
    {
        float s[4] = {0, 0, 0, 0}, ss[4] = {0, 0, 0, 0};
#pragma unroll
        for (int i = 0; i < 8; ++i) {
            float bias = b2f(ws[OFF_B2 + (ntb + i) * 16 + c]);
#pragma unroll
            for (int r = 0; r < 4; ++r) {
                float v = acc2[i][r] + bias;
                acc2[i][r] = v;
                s[r] += v; ss[r] += v * v;
            }
        }
#pragma unroll
        for (int m = 1; m <= 8; m <<= 1)
#pragma unroll
            for (int r = 0; r < 4; ++r) {
                s[r]  += __shfl_xor(s[r],  m, 64);
                ss[r] += __shfl_xor(ss[r], m, 64);
            }
        if (c == 0)
#pragma unroll
            for (int r = 0; r < 4; ++r) {
                SS[(h * 16 + row + r) * 2 + 0] = s[r];
                SS[(h * 16 + row + r) * 2 + 1] = ss[r];
            }
        __syncthreads();   // bar3: LN2 stats (all GEMM2 Hs reads also done)
#pragma unroll
        for (int r = 0; r < 4; ++r) {
            float st = SS[(0 * 16 + row + r) * 2 + 0] + SS[(1 * 16 + row + r) * 2 + 0];
            float sq = SS[(0 * 16 + row + r) * 2 + 1] + SS[(1 * 16 + row + r) * 2 + 1];
            float mean = st * (1.0f / 256.0f);
            float var  = fmaxf(sq * (1.0f / 256.0f) - mean * mean, 0.0f);
            s[r] = mean; ss[r] = rsqrtf(var + 1e-5f);
        }
#pragma unroll
        for (int i = 0; i < 8; ++i) {
            const int nt = ntb + i;
            float gg = b2f(ws[OFF_G2 + nt * 16 + c]);
            float bb = b2f(ws[OFF_BE2 + nt * 16 + c]);
            float y[4];
#pragma unroll
            for (int r = 0; r < 4; ++r)
                y[r] = fmaxf((acc2[i][r] - s[r]) * ss[r] * gg + bb, 0.0f);
            unsigned int u01 = cvtpk(y[0], y[1]);
            unsigned int u23 = cvtpk(y[2], y[3]);
            Hs[(row + 0) * HPAD + nt * 16 + c] = (short)(u01 & 0xffffu);
            Hs[(row + 1) * HPAD + nt * 16 + c] = (short)(u01 >> 16);
            Hs[(row + 2) * HPAD + nt * 16 + c] = (short)(u23 & 0xffffu);
            Hs[(row + 3) * HPAD + nt * 16 + c] = (short)(u23 >> 16);
        }
    }
    __syncthreads();   // bar4: Hs(v2) ready, SS(LN2) reads done

    // ===== GEMM3 (split): wave h computes cols [h*32, +32); softmax merged-bar ===
    // No max-subtraction (logits bounded, exp-safe). Unnormalized e -> Ps
    // (separate buffer); per-row partial sums -> SS slot1. One barrier.
    f4v acc3[2];
#pragma unroll
    for (int t = 0; t < 2; ++t) acc3[t] = (f4v){0.f, 0.f, 0.f, 0.f};
#pragma unroll
    for (int ks = 0; ks < 8; ++ks) {
        s8v af = *(const s8v*)&Hs[c * HPAD + ks * 32 + q * 8];
#pragma unroll
        for (int t = 0; t < 2; ++t) {
            const int nt = h * 2 + t;
            s8v bf_ = *(const s8v*)(ws + OFF_W3F + ((nt * 8 + ks) * 64 + l) * 8);
            acc3[t] = __builtin_amdgcn_mfma_f32_16x16x32_bf16(af, bf_, acc3[t], 0, 0, 0);
        }
    }
    {
        float sum[4] = {0, 0, 0, 0};
#pragma unroll
        for (int t = 0; t < 2; ++t) {
            const int nt = h * 2 + t;
            const float bias = b2f(ws[OFF_B3 + nt * 16 + c]);
#pragma unroll
            for (int r = 0; r < 4; ++r) {
                float e = __expf(acc3[t][r] + bias);
                Ps[(row + r) * PPAD + nt * 16 + c] = e;   // unnormalized
                sum[r] += e;
            }
        }
#pragma unroll
        for (int m = 1; m <= 8; m <<= 1)
#pragma unroll
            for (int r = 0; r < 4; ++r)
                sum[r] += __shfl_xor(sum[r], m, 64);
        if (c == 0)
#pragma unroll
            for (int r = 0; r < 4; ++r)
                SS[(h * 16 + row + r) * 2 + 1] = sum[r];
    }
    __syncthreads();   // bar5: Ps(e) + partial sums visible

    // ===== Toeplitz: out[m,i] = (1/S_m) * sum_{s<=i} e[m,s]*a[m,i-s] =====
    // 4 j's per wave. Normalize during half-pack (p<=1, no overflow).
    // r starts as a[i]; step s: acc += p[s]*r; r = wave_shr(r) (0-fill).
#pragma unroll
    for (int jj = 0; jj < 4; ++jj) {
        const int j = h * 4 + jj;
        const int m0 = j, m1 = j + 8;
        float S0 = SS[(0 * 16 + m0) * 2 + 1] + SS[(1 * 16 + m0) * 2 + 1];
        float S1 = SS[(0 * 16 + m1) * 2 + 1] + SS[(1 * 16 + m1) * 2 + 1];
        const float i0 = __builtin_amdgcn_rcpf(S0);
        const float i1 = __builtin_amdgcn_rcpf(S1);
        __half2 pph = __floats2half2_rn(Ps[m0 * PPAD + l] * i0,
                                        Ps[m1 * PPAD + l] * i1);
        const int ppi = h2i(pph);
        __half2 aah = __floats2half2_rn(loadS<BF16>(a_bits, (grow0 + m0) * 64 + l),
                                        loadS<BF16>(a_bits, (grow0 + m1) * 64 + l));
        int rr = h2i(aah);
        __half2 acc = __float2half2_rn(0.0f);
#pragma unroll
        for (int s = 0; s < 64; ++s) {
            const int spi = __builtin_amdgcn_readlane(ppi, s);
            acc = __hfma2(i2h(spi), i2h(rr), acc);
            if (s < 63)
                rr = __builtin_amdgcn_update_dpp(0, rr, 0x138, 0xF, 0xF, true); // wave_shr:1
        }
        storeO<BF16>(out, (grow0 + m0) * 64 + l, __low2float(acc));
        storeO<BF16>(out, (grow0 + m1) * 64 + l, __high2float(acc));
    }
}

__global__ __launch_bounds__(128, 4) void shiftdec_kernel(
    const void* __restrict__ a_bits, const void* __restrict__ shifts,
    const unsigned short* __restrict__ ws, void* __restrict__ out)
{
    __shared__ __align__(16) short Hs[16 * HPAD];        // 8448 B
    __shared__ __align__(16) float Ps[16 * PPAD];        // 4352 B (separate: no overlay)
    __shared__ __align__(16) float SSb[2 * 16 * 2];      // 256 B stat exchange

    if (probe_bf16(a_bits))
        pipeline<true>(a_bits, shifts, ws, out, Hs, Ps, SSb);
    else
        pipeline<false>(a_bits, shifts, ws, out, Hs, Ps, SSb);
}

extern "C" void kernel_launch(void* const* d_in, const int* in_sizes, int n_in,
                              void* d_out, int out_size, void* d_ws, size_t ws_size,
                              hipStream_t stream) {
    const int B = in_sizes[0] / 64;      // rows (32768)
    const int grid = B / 16;             // 16 rows per block -> 2048 blocks of 128

    hipLaunchKernelGGL(convert_kernel, dim3(49), dim3(256), 0, stream,
                       d_in[0], d_in[2], d_in[6], d_in[10],
                       d_in[3], d_in[4], d_in[5], d_in[7], d_in[8], d_in[9], d_in[11],
                       (unsigned short*)d_ws);
    hipLaunchKernelGGL(shiftdec_kernel, dim3(grid), dim3(128), 0, stream,
                       d_in[0], d_in[1], (const unsigned short*)d_ws, d_out);
}